// Round 11
// baseline (679.034 us; speedup 1.0000x reference)
//
#include <hip/hip_runtime.h>
#include <cstdint>
#include <cstddef>

#define M_ROWS 32768   // B*N
#define CDIM   512
#define KRANK  150
#define KPAD   160     // padded rank for MFMA (zeros beyond 150)

typedef __bf16 bf16x8 __attribute__((ext_vector_type(8)));
typedef float  f32x4  __attribute__((ext_vector_type(4)));

union U16B { uint4 u; bf16x8 b; };
static __device__ __forceinline__ bf16x8 u2b(uint4 u) { U16B x; x.u = u; return x.b; }

static __device__ __forceinline__ unsigned short f2bf(float f) {
  uint32_t u = __float_as_uint(f);
  u += 0x7fffu + ((u >> 16) & 1u);
  return (unsigned short)(u >> 16);
}

// split 8 fp32 into hi/lo bf16 (hi = RNE(v), lo = RNE(v - hi)); err ~2^-16 rel
static __device__ __forceinline__ void cvt8(float4 a, float4 b, uint4& h, uint4& l) {
  float v[8] = {a.x, a.y, a.z, a.w, b.x, b.y, b.z, b.w};
  unsigned short hs[8], ls[8];
#pragma unroll
  for (int i = 0; i < 8; ++i) {
    hs[i] = f2bf(v[i]);
    const float hf = __uint_as_float((uint32_t)hs[i] << 16);
    ls[i] = f2bf(v[i] - hf);
  }
  h = *(uint4*)&hs[0];
  l = *(uint4*)&ls[0];
}

// async global->LDS, 16B per lane (dest = wave-uniform base + lane*16)
static __device__ __forceinline__ void glds16(const void* g, void* l) {
  __builtin_amdgcn_global_load_lds(
      (const __attribute__((address_space(1))) unsigned int*)g,
      (__attribute__((address_space(3))) unsigned int*)l, 16, 0, 0);
}

// swizzled 16B-cell index used by mgemm LDS tiles (row 0..127, k4 0..3)
static __device__ __forceinline__ int sa16f(int row, int k4) {
  return ((row >> 1) << 3) + ((((row & 1) << 2) | k4) ^ ((row >> 1) & 7));
}

// ============== merged converter: x A-images + W B-images in ONE dispatch ==============
// bid < 4096: x job (mtile = bid>>4, kt = bid&15) -> Ximg cells [0,512)=AH, [512,1024)=AL.
// bid >= 4096: W job (as before): [Wv:32][Wres:32][Wq:16][Wk:16]; image per (ntile,kt) =
// 2048 cells: [0,1024)=BH (rows 0-127 at sa16, 128-255 at 512+sa16), [1024,2048)=BL.
// Rows >= N zeroed (kills in-kernel masking). Grid 4192 x 512.
__global__ __launch_bounds__(512)
void cvt_all(const float* __restrict__ X, unsigned short* __restrict__ Ximg,
             const float* __restrict__ Wv, const float* __restrict__ Wres,
             const float* __restrict__ Wq, const float* __restrict__ Wk,
             unsigned short* __restrict__ WvC, unsigned short* __restrict__ WresC,
             unsigned short* __restrict__ WqC, unsigned short* __restrict__ WkC)
{
  const int tid = threadIdx.x;
  const int srow = tid >> 2, sk4 = tid & 3;
  const int sa = sa16f(srow, sk4);

  if (blockIdx.x < 4096) {            // ---- x A-image job ----
    const int bid = blockIdx.x;
    const int mt = bid >> 4, kt = bid & 15;
    const float* xp = X + (size_t)(mt * 128 + srow) * 512 + kt * 32 + sk4 * 8;
    const float4 v0 = *(const float4*)(xp);
    const float4 v1 = *(const float4*)(xp + 4);
    uint4 h4, l4; cvt8(v0, v1, h4, l4);
    unsigned short* ib = Ximg + (size_t)bid * 8192;   // 1024 cells * 8 ush
    *(uint4*)&ib[(size_t)sa * 8]         = h4;
    *(uint4*)&ib[(size_t)(512 + sa) * 8] = l4;
    return;
  }

  int job = blockIdx.x - 4096;        // ---- W B-image job ----
  const float* W; unsigned short* img; int N;
  if (job < 32)      { W = Wv;   img = WvC;   N = 512; }
  else if (job < 64) { W = Wres; img = WresC; N = 512; job -= 32; }
  else if (job < 80) { W = Wq;   img = WqC;   N = KRANK; job -= 64; }
  else               { W = Wk;   img = WkC;   N = KRANK; job -= 80; }
  const int nt = (N == 512) ? (job >> 4) : 0;
  const int kt = job & 15;

  unsigned short* ib = img + (size_t)(nt * 16 + kt) * 16384;  // 2048 cells * 8 ush
#pragma unroll
  for (int h = 0; h < 2; ++h) {
    const int row = nt * 256 + h * 128 + srow;
    float4 v0 = make_float4(0.f, 0.f, 0.f, 0.f), v1 = v0;
    if (row < N) {
      v0 = *(const float4*)&W[(size_t)row * 512 + kt * 32 + sk4 * 8];
      v1 = *(const float4*)&W[(size_t)row * 512 + kt * 32 + sk4 * 8 + 4];
    }
    uint4 h4, l4; cvt8(v0, v1, h4, l4);
    const int cell = h * 512 + sa;
    *(uint4*)&ib[(size_t)cell * 8]          = h4;
    *(uint4*)&ib[(size_t)(1024 + cell) * 8] = l4;
  }
}

// ================= MFMA hi/lo GEMM (fp32-accurate via 3-product bf16) =================
// out[m][n] = sum_k A[m][k]*W[n][k] (+bias).  M=32768, K=512.
// MODE 4/1: tile 128m x 256n, 8 waves 2m x 4n, wave 64x64 = 4x4 frags.
// MODE 5 (merged Q/K proj, bx=0->Q bx=1->K): tile 128m x 160n, 8 waves 4m x 2n,
//   wave 32x80 = 2x5 frags -> skips the all-zero cols 160-255 (37.5% less MFMA).
// AGL=1: A staged via 2 glds16 from pre-converted Ximg. AGL=0: reg-stage + cvt8.
template<int MODE, int AGL>
__global__ __launch_bounds__(512, 4)
void mgemm_nt(const float* __restrict__ A, const unsigned short* __restrict__ Ximg,
              const unsigned short* __restrict__ Wimg,
              const float* __restrict__ bias, float* __restrict__ out,
              const float* __restrict__ xres, const float* __restrict__ gammap,
              unsigned short* __restrict__ aux,
              const unsigned short* __restrict__ Wimg2,
              const float* __restrict__ bias2,
              unsigned short* __restrict__ aux2)
{
  // regions (ushort offsets): AH 0 (4096), AL 4096, BH 8192 (8192), BL 16384. 49152 B.
  __shared__ __align__(16) unsigned short lds[24576];
  constexpr int NI  = (MODE == 5) ? 2 : 4;    // m-frags per wave
  constexpr int NJ  = (MODE == 5) ? 5 : 4;    // n-frags per wave
  constexpr int NCW = (MODE == 5) ? 80 : 64;  // wave col width
  const int tid = threadIdx.x;
  const int m0  = blockIdx.y * 128;
  const int bx  = blockIdx.x;

  const unsigned short* img = (MODE == 5) ? (bx ? Wimg2 : Wimg)
                                          : Wimg + (size_t)(bx * 16) * 16384;
  const float* bias_u = (MODE == 5 && bx) ? bias2 : bias;
  unsigned short* aux_u = (MODE == 5 && bx) ? aux2 : aux;

  // ---- A staging geometry (AGL=0 path) ----
  const int srow = tid >> 2, sk4 = tid & 3;
  const int sa16 = sa16f(srow, sk4);
  const float* ap = A + (size_t)(m0 + srow) * 512 + sk4 * 8;

  // ---- fragment geometry ----
  const int lane = tid & 63, w = tid >> 6;
  const int wm = (MODE == 5) ? (w >> 1) : (w >> 2);
  const int wn = (MODE == 5) ? (w & 1) : (w & 3);
  const int arb = wm * ((MODE == 5) ? 32 : 64);          // wave m rowbase
  const int cq = lane & 15, quad = lane >> 4;
  const int fsub = (((cq & 1) << 2) | quad) ^ (cq >> 1);
  const int foff = ((cq >> 1) << 3) + fsub;              // lane cell offset

  const unsigned short* ibase = img + (size_t)(w * 64 + lane) * 8;
  const unsigned short* xibase = Ximg + (size_t)(m0 >> 7) * 16 * 8192
                               + (size_t)(w * 64 + lane) * 8;

  f32x4 acc[NI][NJ];
#pragma unroll
  for (int i = 0; i < NI; ++i)
#pragma unroll
    for (int j = 0; j < NJ; ++j) acc[i][j] = (f32x4){0.f, 0.f, 0.f, 0.f};

  for (int kt = 0; kt < 512; kt += 32) {
    uint4 ahi, alo;
    if (AGL == 0) {
      const float4 av0 = *(const float4*)(ap + kt);
      const float4 av1 = *(const float4*)(ap + kt + 4);
      cvt8(av0, av1, ahi, alo);
    }

    __syncthreads();   // A: previous tile's readers done
    if (AGL == 0) {
      *(uint4*)&lds[       sa16 * 8] = ahi;
      *(uint4*)&lds[4096 + sa16 * 8] = alo;
    } else {
      const unsigned short* xs = xibase + (size_t)(kt >> 5) * 8192;
      glds16(xs,                   &lds[(w * 64) * 8]);
      glds16(xs + (size_t)512 * 8, &lds[4096 + (w * 64) * 8]);
    }
    const unsigned short* src = ibase + (size_t)(kt >> 5) * 16384;
    if (MODE == 5) {
      glds16(src,                         &lds[8192 + (w * 64) * 8]);
      if (w < 2) glds16(src + 4096,       &lds[8192 + (512 + w * 64) * 8]);
      glds16(src + 8192,                  &lds[8192 + (1024 + w * 64) * 8]);
      if (w < 2) glds16(src + 12288,      &lds[8192 + (1536 + w * 64) * 8]);
    } else {
#pragma unroll
      for (int c = 0; c < 4; ++c)
        glds16(src + (size_t)c * 4096, &lds[8192 + (c * 512 + w * 64) * 8]);
    }
    __syncthreads();   // B: ds + vmem->lds drained, staging visible

    bf16x8 ah[NI], al_[NI];
#pragma unroll
    for (int i = 0; i < NI; ++i) {
      const int ac = (arb + i * 16) * 4 + foff;
      ah[i]  = u2b(*(const uint4*)&lds[       ac * 8]);
      al_[i] = u2b(*(const uint4*)&lds[4096 + ac * 8]);
    }
#pragma unroll
    for (int j = 0; j < NJ; ++j) {
      const int rb = wn * NCW + j * 16;
      const int bc = (rb >> 7) * 512 + (rb & 127) * 4 + foff;
      const bf16x8 bh = u2b(*(const uint4*)&lds[8192  + bc * 8]);
      const bf16x8 bl = u2b(*(const uint4*)&lds[16384 + bc * 8]);
#pragma unroll
      for (int i = 0; i < NI; ++i) {
        acc[i][j] = __builtin_amdgcn_mfma_f32_16x16x32_bf16(ah[i],  bh, acc[i][j], 0, 0, 0);
        acc[i][j] = __builtin_amdgcn_mfma_f32_16x16x32_bf16(al_[i], bh, acc[i][j], 0, 0, 0);
        acc[i][j] = __builtin_amdgcn_mfma_f32_16x16x32_bf16(ah[i],  bl, acc[i][j], 0, 0, 0);
      }
    }
  }

  // ---- epilogue: C frag elem (i,j,r): m = m0+arb+i*16+quad*4+r, n = n0b+wn*NCW+j*16+cq
  const int n0b = (MODE == 5) ? 0 : bx * 256;
  const int mb = m0 + arb + quad * 4;
  const int nb = n0b + wn * NCW + cq;

  if (MODE == 1) {
    const float g = gammap[0];
#pragma unroll
    for (int j = 0; j < NJ; ++j) {
      const float bvj = bias_u[nb + j * 16];
#pragma unroll
      for (int i = 0; i < NI; ++i) {
#pragma unroll
        for (int r = 0; r < 4; ++r) {
          const size_t off = (size_t)(mb + i * 16 + r) * 512 + (nb + j * 16);
          out[off] = fmaf(g, acc[i][j][r] + bvj, xres[off]);
        }
      }
    }
  } else if (MODE == 4) {  // VT[b][n][key] bf16
    const int b = m0 >> 12;
    const int key0 = (m0 & 4095) + arb + quad * 4;
#pragma unroll
    for (int j = 0; j < NJ; ++j) {
      const float bvj = bias_u[nb + j * 16];
      const size_t rowo = (size_t)(b * 512 + nb + j * 16) * 4096;
#pragma unroll
      for (int i = 0; i < NI; ++i) {
        unsigned short o4[4];
#pragma unroll
        for (int r = 0; r < 4; ++r) o4[r] = f2bf(acc[i][j][r] + bvj);
        uint2 o;
        o.x = (unsigned int)o4[0] | ((unsigned int)o4[1] << 16);
        o.y = (unsigned int)o4[2] | ((unsigned int)o4[3] << 16);
        *(uint2*)&aux_u[rowo + key0 + i * 16] = o;
      }
    }
  } else {  // MODE 5: Q (bx=0) / K (bx=1); n = wn*80 + j*16 + cq in [0,160)
#pragma unroll
    for (int j = 0; j < NJ; ++j) {
      const int n = nb + j * 16;
      const float bvj = (n < KRANK) ? bias_u[n] : 0.f;
#pragma unroll
      for (int i = 0; i < NI; ++i) {
#pragma unroll
        for (int r = 0; r < 4; ++r) {
          const int m = mb + i * 16 + r;
          float v = (n < KRANK) ? (acc[i][j][r] + bvj) : 0.f;
          if (bx == 0 && n < KRANK) out[(size_t)m * KRANK + n] = v;
          const unsigned short hh = f2bf(v);
          aux_u[(size_t)m * 320 + n] = hh;
          const float hf = __uint_as_float(((uint32_t)hh) << 16);
          aux_u[(size_t)m * 320 + 160 + n] = f2bf(v - hf);
        }
      }
    }
  }
}

// ================= MFMA flash attention (v13: async dbuf glds16 staging) =============
// 256 blocks: b = bid&7 (XCD-affine), qt = bid>>3. Block = 128 q-rows x 512 cols.
// vs v12: K/V staged by global_load_lds directly into DOUBLE-BUFFERED LDS (no
// reg-prefetch, no ds_writes, 2 barriers/iter instead of 3). Layouts (m173 rule:
// linear LDS dest + per-lane swizzled global source + swizzled read):
//   klds: 32x320 unpadded; cell(key,c4) holds global (key,(c4&56)|((c4&7)^(key&7)))
//     -> read bank = 4*((t&7)^cq), conflict-free; glds16 src 128B-coalesced.
//   vtl: cell L' holds (col,plane) with L=(L'>>3)*8+((L'&7)^((L'>>3)&7)), col=L>>2,
//     plane=L&3 -> PV read bank = 4*(((cq&1)*4+quad)^(cq>>1)), conflict-free;
//     glds16 src = 2x64B chunks per 8 lanes (same coalescing as v12 prefetch).
// S swapped mfma(K,Q) + scalar softmax + shared-V PV unchanged from v12 (361 us R9).
__global__ __launch_bounds__(512, 2)
void attn_mfma(const unsigned short* __restrict__ Qc,   // [32768][320] hi|lo
               const unsigned short* __restrict__ Kc,   // [32768][320] hi|lo
               const unsigned short* __restrict__ VT,   // [8][512][4096] bf16
               float* __restrict__ O)                   // [32768][512] fp32
{
  // ush offsets: kbuf 2x10240 @0 | vbuf 2x16384 @20480 | pbuf 2x5120 @53248
  // | alw 2x128f32 @63488 | updf 2x8u32 @64000 | linv 128f32 @64032. 128576 B.
  __shared__ __align__(16) unsigned short smem[64288];
  constexpr int KB = 0, VB = 20480, PB = 53248, AW = 63488, UF = 64000, LV = 64032;

  const int bid = blockIdx.x;
  const int b   = bid & 7;                  // XCD-affine batch
  const int qt  = bid >> 3;                 // 0..31
  const int r0  = (b << 12) + qt * 128;

  const int tid  = threadIdx.x;             // 0..511
  const int w    = tid >> 6;                // 0..7
  const int lane = tid & 63;
  const int quad = lane >> 4;
  const int cq   = lane & 15;
  const int cqx  = cq & 7;
  const int p    = w >> 1;                  // PV row-pair
  const int h    = w & 1;                   // PV col-half

  // ---- persistent Q fragments (B-operand layout), rows r0+w*16+cq ----
  bf16x8 qhi[5], qlo[5];
  {
    const size_t qrow = (size_t)(r0 + w * 16 + cq) * 320;
#pragma unroll
    for (int c = 0; c < 5; ++c) {
      qhi[c] = u2b(*(const uint4*)(Qc + qrow + c * 32 + quad * 8));
      qlo[c] = u2b(*(const uint4*)(Qc + qrow + 160 + c * 32 + quad * 8));
    }
  }

  f32x4 acc4[32];   // [ct] = rows tile 2p, [16+ct] = rows tile 2p+1; cols h*256+ct*16
#pragma unroll
  for (int i = 0; i < 32; ++i) acc4[i] = (f32x4){0.f, 0.f, 0.f, 0.f};
  float mreg = -3.0e38f, lreg = 0.f;        // scalar: lane owns row cq

  // ---- glds16 staging geometry (per-lane, loop-invariant) ----
  const unsigned short* kbase = Kc + (size_t)(b * 4096) * 320;
  // K: 1280 cells, 20 slots x 64; wave w -> slots {w, 8+w, 16+w (w<4)}
  int koff0, koff1, koff2;
  {
    int cell, key, c4l, oc4;
    cell = w * 64 + lane;        key = cell / 40; c4l = cell - key * 40;
    oc4 = (c4l & 56) | ((c4l & 7) ^ (key & 7)); koff0 = key * 320 + oc4 * 8;
    cell = (8 + w) * 64 + lane;  key = cell / 40; c4l = cell - key * 40;
    oc4 = (c4l & 56) | ((c4l & 7) ^ (key & 7)); koff1 = key * 320 + oc4 * 8;
    cell = (16 + w) * 64 + lane; key = cell / 40; c4l = cell - key * 40;
    oc4 = (c4l & 56) | ((c4l & 7) ^ (key & 7)); koff2 = key * 320 + oc4 * 8;
  }
  // V: 2048 cells, 32 slots x 64; wave w -> slots w*4..w*4+3
  const unsigned short *vp0, *vp1, *vp2, *vp3;
  {
    int Lp, g, L;
    Lp = (w * 4 + 0) * 64 + lane; g = Lp >> 3; L = (g << 3) | ((Lp & 7) ^ (g & 7));
    vp0 = VT + ((size_t)(b * 512 + (L >> 2))) * 4096 + (L & 3) * 8;
    Lp = (w * 4 + 1) * 64 + lane; g = Lp >> 3; L = (g << 3) | ((Lp & 7) ^ (g & 7));
    vp1 = VT + ((size_t)(b * 512 + (L >> 2))) * 4096 + (L & 3) * 8;
    Lp = (w * 4 + 2) * 64 + lane; g = Lp >> 3; L = (g << 3) | ((Lp & 7) ^ (g & 7));
    vp2 = VT + ((size_t)(b * 512 + (L >> 2))) * 4096 + (L & 3) * 8;
    Lp = (w * 4 + 3) * 64 + lane; g = Lp >> 3; L = (g << 3) | ((Lp & 7) ^ (g & 7));
    vp3 = VT + ((size_t)(b * 512 + (L >> 2))) * 4096 + (L & 3) * 8;
  }
  // PV V-read lane offset (ush): bank-verified conflict-free
  const int vlo = h * 8192 + ((cq >> 1) << 6) + ((((cq & 1) * 4 + quad) ^ (cq >> 1)) << 3);

  // ---- prologue: stage tile 0 -> buf 0 ----
  {
    unsigned short* kd = &smem[KB];
    glds16(kbase + koff0, kd + w * 512);
    glds16(kbase + koff1, kd + (8 + w) * 512);
    if (w < 4) glds16(kbase + koff2, kd + (16 + w) * 512);
    unsigned short* vd = &smem[VB + (w * 4) * 512];
    glds16(vp0, vd);        glds16(vp1, vd + 512);
    glds16(vp2, vd + 1024); glds16(vp3, vd + 1536);
  }
  __syncthreads();   // tile 0 staged (vmcnt drained by barrier)

  for (int kt = 0; kt < 128; ++kt) {
    const int buf = kt & 1;
    const unsigned short* k0 = &smem[KB + buf * 10240] + cq * 320;
    const unsigned short* k1 = k0 + 16 * 320;

    // ---- S phase (swapped): lane holds row cq, keys quad*4+r / 16+quad*4+r ----
    f32x4 S0 = (f32x4){0.f, 0.f, 0.f, 0.f};
    f32x4 S1 = (f32x4){0.f, 0.f, 0.f, 0.f};
    __builtin_amdgcn_s_setprio(1);
#pragma unroll
    for (int c = 0; c < 5; ++c) {
      const int thi = c * 4 + quad, tlo = thi + 20;
      const int ohi = ((thi & 56) | ((thi & 7) ^ cqx)) * 8;
      const int olo = ((tlo & 56) | ((tlo & 7) ^ cqx)) * 8;
      const bf16x8 kh0 = u2b(*(const uint4*)(k0 + ohi));
      const bf16x8 kl0 = u2b(*(const uint4*)(k0 + olo));
      const bf16x8 kh1 = u2b(*(const uint4*)(k1 + ohi));
      const bf16x8 kl1 = u2b(*(const uint4*)(k1 + olo));
      S0 = __builtin_amdgcn_mfma_f32_16x16x32_bf16(kh0, qhi[c], S0, 0, 0, 0);
      S1 = __builtin_amdgcn_mfma_f32_16x16x32_bf16(kh1, qhi[c], S1, 0, 0, 0);
      S0 = __builtin_amdgcn_mfma_f32_16x16x32_bf16(kl0, qhi[c], S0, 0, 0, 0);
      S1 = __builtin_amdgcn_mfma_f32_16x16x32_bf16(kl1, qhi[c], S1, 0, 0, 0);
      S0 = __builtin_amdgcn_mfma_f32_16x16x32_bf16(kh0, qlo[c], S0, 0, 0, 0);
      S1 = __builtin_amdgcn_mfma_f32_16x16x32_bf16(kh1, qlo[c], S1, 0, 0, 0);
    }
    __builtin_amdgcn_s_setprio(0);

    // ---- scalar online softmax for row cq (defer-max THR=8) ----
    unsigned short* pw = &smem[PB + buf * 5120 + w * 640];
    float t = fmaxf(fmaxf(S0[0], S0[1]), fmaxf(S0[2], S0[3]));
    t = fmaxf(t, fmaxf(fmaxf(S1[0], S1[1]), fmaxf(S1[2], S1[3])));
    t = fmaxf(t, __shfl_xor(t, 16));
    t = fmaxf(t, __shfl_xor(t, 32));
    const bool need = (t > mreg + 8.f);
    const float mn = need ? t : mreg;
    const float al = need ? __expf(mreg - mn) : 1.f;
    mreg = mn;
    float pvx[8];
#pragma unroll
    for (int r = 0; r < 4; ++r) { pvx[r] = __expf(S0[r] - mn); pvx[4 + r] = __expf(S1[r] - mn); }
    float ts = ((pvx[0] + pvx[1]) + (pvx[2] + pvx[3])) + ((pvx[4] + pvx[5]) + (pvx[6] + pvx[7]));
    ts += __shfl_xor(ts, 16);
    ts += __shfl_xor(ts, 32);
    lreg = lreg * al + ts;
    {
      unsigned short q0 = f2bf(pvx[0]), q1 = f2bf(pvx[1]), q2 = f2bf(pvx[2]), q3 = f2bf(pvx[3]);
      unsigned short q4 = f2bf(pvx[4]), q5 = f2bf(pvx[5]), q6 = f2bf(pvx[6]), q7 = f2bf(pvx[7]);
      uint2 o0, o1;
      o0.x = (unsigned)q0 | ((unsigned)q1 << 16); o0.y = (unsigned)q2 | ((unsigned)q3 << 16);
      o1.x = (unsigned)q4 | ((unsigned)q5 << 16); o1.y = (unsigned)q6 | ((unsigned)q7 << 16);
      *(uint2*)&pw[cq * 40 + quad * 4]      = o0;   // keys quad*4..+3
      *(uint2*)&pw[cq * 40 + 16 + quad * 4] = o1;   // keys 16+quad*4..+3
    }
    float* alwB = (float*)&smem[AW] + buf * 128;
    if (lane < 16) alwB[w * 16 + lane] = al;
    unsigned* updB = (unsigned*)&smem[UF] + buf * 8;
    const bool anyu = __any(need);
    if (lane == 0) updB[w] = anyu ? 1u : 0u;

    __syncthreads();  // C: P/alpha/upd visible; tile kt-1 fully consumed by all waves

    // ---- stage tile kt+1 -> buf^1 (in flight during PV, drained at end barrier) ----
    if (kt < 127) {
      const int nbuf = buf ^ 1;
      const unsigned short* ks = kbase + (size_t)(kt + 1) * 10240;
      unsigned short* kd = &smem[KB + nbuf * 10240];
      glds16(ks + koff0, kd + w * 512);
      glds16(ks + koff1, kd + (8 + w) * 512);
      if (w < 4) glds16(ks + koff2, kd + (16 + w) * 512);
      const int vo = (kt + 1) * 32;
      unsigned short* vd = &smem[VB + nbuf * 16384 + (w * 4) * 512];
      glds16(vp0 + vo, vd);        glds16(vp1 + vo, vd + 512);
      glds16(vp2 + vo, vd + 1024); glds16(vp3 + vo, vd + 1536);
    }

    // ---- PV phase: rows tiles {2p,2p+1} x cols [h*256, h*256+256) ----
    const unsigned short* pb = &smem[PB + buf * 5120 + (2 * p) * 640 + cq * 40 + quad * 8];
    const bf16x8 pa0 = u2b(*(const uint4*)pb);
    const bf16x8 pa1 = u2b(*(const uint4*)(pb + 640));

    if (updB[2 * p] | updB[2 * p + 1]) {   // rare under defer-max
      float aA[4], aB[4];
#pragma unroll
      for (int r = 0; r < 4; ++r) {
        aA[r] = alwB[(2 * p) * 16 + quad * 4 + r];
        aB[r] = alwB[(2 * p + 1) * 16 + quad * 4 + r];
      }
#pragma unroll
      for (int ct = 0; ct < 16; ++ct) {
#pragma unroll
        for (int r = 0; r < 4; ++r) {
          acc4[ct][r]      *= aA[r];
          acc4[16 + ct][r] *= aB[r];
        }
      }
    }

    const unsigned short* vbL = &smem[VB + buf * 16384] + vlo;
    __builtin_amdgcn_s_setprio(1);
#pragma unroll
    for (int ct = 0; ct < 16; ++ct) {
      const bf16x8 vb = u2b(*(const uint4*)(vbL + ct * 512));
      acc4[ct]      = __builtin_amdgcn_mfma_f32_16x16x32_bf16(pa0, vb, acc4[ct], 0, 0, 0);
      acc4[16 + ct] = __builtin_amdgcn_mfma_f32_16x16x32_bf16(pa1, vb, acc4[16 + ct], 0, 0, 0);
    }
    __builtin_amdgcn_s_setprio(0);

    __syncthreads();  // end: next-tile glds16 drained; buf roles swap
  }

  // ---- epilogue: O = acc/l, cross-wave 1/l via LDS, staged through LDS ----
  float* linvp = (float*)&smem[LV];
  if (lane < 16) linvp[w * 16 + lane] = 1.f / lreg;
  __syncthreads();  // linv visible; all waves past final loop barrier

  float invv[2][4];
#pragma unroll
  for (int rt = 0; rt < 2; ++rt)
#pragma unroll
    for (int r = 0; r < 4; ++r)
      invv[rt][r] = linvp[(2 * p + rt) * 16 + quad * 4 + r];

  float* ep = (float*)smem + w * 1088;     // 16 rows x 68 fp32 per wave (4352 B)
#pragma unroll
  for (int rt = 0; rt < 2; ++rt) {
    const int rowb = r0 + (2 * p + rt) * 16;
#pragma unroll
    for (int g = 0; g < 4; ++g) {
#pragma unroll
      for (int ii = 0; ii < 4; ++ii)
#pragma unroll
        for (int r = 0; r < 4; ++r)
          ep[(quad * 4 + r) * 68 + ii * 16 + cq] = acc4[rt * 16 + g * 4 + ii][r] * invv[rt][r];
      // wave-private RAW; ds ops complete in order per wave
#pragma unroll
      for (int t2 = 0; t2 < 4; ++t2) {
        const int flat4 = t2 * 64 + lane;  // 0..255 float4 units (16 rows x 16)
        const int row = flat4 >> 4;        // 0..15
        const int c4 = flat4 & 15;
        const float4 val = *(const float4*)&ep[row * 68 + c4 * 4];
        *(float4*)&O[(size_t)(rowb + row) * CDIM + h * 256 + g * 64 + c4 * 4] = val;
      }
    }
  }
}

extern "C" void kernel_launch(void* const* d_in, const int* in_sizes, int n_in,
                              void* d_out, int out_size, void* d_ws, size_t ws_size,
                              hipStream_t stream)
{
  const float* x     = (const float*)d_in[0];
  const float* Wq    = (const float*)d_in[1];
  const float* bq    = (const float*)d_in[2];
  const float* Wk    = (const float*)d_in[3];
  const float* bk    = (const float*)d_in[4];
  const float* Wv    = (const float*)d_in[5];
  const float* bv    = (const float*)d_in[6];
  const float* Wres  = (const float*)d_in[7];
  const float* bres  = (const float*)d_in[8];
  const float* gamma = (const float*)d_in[9];

  float* seg_map  = (float*)d_out;                         // 32768 x 150
  float* feat_map = seg_map + (size_t)M_ROWS * KRANK;      // 32768 x 512

  unsigned short* Qcomb = (unsigned short*)d_ws;                       // [32768][320]
  unsigned short* Kcomb = Qcomb + (size_t)M_ROWS * 320;                // [32768][320]
  unsigned short* VTb   = Kcomb + (size_t)M_ROWS * 320;                // [8][512][4096]
  float*          feats = (float*)(VTb + (size_t)M_ROWS * CDIM);       // [32768][512]
  unsigned short* WvC   = (unsigned short*)(feats + (size_t)M_ROWS * CDIM); // 2x16 images
  unsigned short* WresC = WvC   + (size_t)2 * 16 * 16384;
  unsigned short* WqC   = WresC + (size_t)2 * 16 * 16384;              // 1x16 images
  unsigned short* WkC   = WqC   + (size_t)16 * 16384;
  // x A-images (64 MB) overlay the feats region: consumed by mgemm<5>/<4>, then
  // attn overwrites the region with feats (stream-ordered, safe).
  unsigned short* XiC   = (unsigned short*)feats;                      // 4096 x 8192 ush

  cvt_all<<<dim3(4192), dim3(512), 0, stream>>>(x, XiC, Wv, Wres, Wq, Wk, WvC, WresC, WqC, WkC);
  mgemm_nt<5, 1><<<dim3(2, 256), dim3(512), 0, stream>>>(x, XiC, WqC, bq, seg_map, nullptr, nullptr, Qcomb, WkC, bk, Kcomb);
  mgemm_nt<4, 1><<<dim3(2, 256), dim3(512), 0, stream>>>(x, XiC, WvC, bv, nullptr, nullptr, nullptr, VTb, nullptr, nullptr, nullptr);
  attn_mfma<<<dim3(256), dim3(512), 0, stream>>>(Qcomb, Kcomb, VTb, feats);
  mgemm_nt<1, 0><<<dim3(2, 256), dim3(512), 0, stream>>>(feats, nullptr, WresC, bres, feat_map, x, gamma, nullptr, nullptr, nullptr, nullptr);
}

// Round 12
// 653.349 us; speedup vs baseline: 1.0393x; 1.0393x over previous
//
#include <hip/hip_runtime.h>
#include <cstdint>
#include <cstddef>

#define M_ROWS 32768   // B*N
#define CDIM   512
#define KRANK  150
#define KPAD   160     // padded rank for MFMA (zeros beyond 150)

typedef __bf16 bf16x8 __attribute__((ext_vector_type(8)));
typedef float  f32x4  __attribute__((ext_vector_type(4)));

union U16B { uint4 u; bf16x8 b; };
static __device__ __forceinline__ bf16x8 u2b(uint4 u) { U16B x; x.u = u; return x.b; }

static __device__ __forceinline__ unsigned short f2bf(float f) {
  uint32_t u = __float_as_uint(f);
  u += 0x7fffu + ((u >> 16) & 1u);
  return (unsigned short)(u >> 16);
}

// split 8 fp32 into hi/lo bf16 (hi = RNE(v), lo = RNE(v - hi)); err ~2^-16 rel
static __device__ __forceinline__ void cvt8(float4 a, float4 b, uint4& h, uint4& l) {
  float v[8] = {a.x, a.y, a.z, a.w, b.x, b.y, b.z, b.w};
  unsigned short hs[8], ls[8];
#pragma unroll
  for (int i = 0; i < 8; ++i) {
    hs[i] = f2bf(v[i]);
    const float hf = __uint_as_float((uint32_t)hs[i] << 16);
    ls[i] = f2bf(v[i] - hf);
  }
  h = *(uint4*)&hs[0];
  l = *(uint4*)&ls[0];
}

// async global->LDS, 16B per lane (dest = wave-uniform base + lane*16)
static __device__ __forceinline__ void glds16(const void* g, void* l) {
  __builtin_amdgcn_global_load_lds(
      (const __attribute__((address_space(1))) unsigned int*)g,
      (__attribute__((address_space(3))) unsigned int*)l, 16, 0, 0);
}

// swizzled 16B-cell index used by mgemm LDS tiles (row 0..127, k4 0..3)
static __device__ __forceinline__ int sa16f(int row, int k4) {
  return ((row >> 1) << 3) + ((((row & 1) << 2) | k4) ^ ((row >> 1) & 7));
}

// ============== merged converter: x A-images + W B-images in ONE dispatch ==============
// bid < 4096: x job (mtile = bid>>4, kt = bid&15) -> Ximg cells [0,512)=AH, [512,1024)=AL.
// bid >= 4096: W job: [Wv:32][Wres:32][Wq:16][Wk:16]; image per (ntile,kt) =
// 2048 cells: [0,1024)=BH (rows 0-127 at sa16, 128-255 at 512+sa16), [1024,2048)=BL.
// Rows >= N zeroed (kills in-kernel masking). Grid 4192 x 512.
__global__ __launch_bounds__(512)
void cvt_all(const float* __restrict__ X, unsigned short* __restrict__ Ximg,
             const float* __restrict__ Wv, const float* __restrict__ Wres,
             const float* __restrict__ Wq, const float* __restrict__ Wk,
             unsigned short* __restrict__ WvC, unsigned short* __restrict__ WresC,
             unsigned short* __restrict__ WqC, unsigned short* __restrict__ WkC)
{
  const int tid = threadIdx.x;
  const int srow = tid >> 2, sk4 = tid & 3;
  const int sa = sa16f(srow, sk4);

  if (blockIdx.x < 4096) {            // ---- x A-image job ----
    const int bid = blockIdx.x;
    const int mt = bid >> 4, kt = bid & 15;
    const float* xp = X + (size_t)(mt * 128 + srow) * 512 + kt * 32 + sk4 * 8;
    const float4 v0 = *(const float4*)(xp);
    const float4 v1 = *(const float4*)(xp + 4);
    uint4 h4, l4; cvt8(v0, v1, h4, l4);
    unsigned short* ib = Ximg + (size_t)bid * 8192;   // 1024 cells * 8 ush
    *(uint4*)&ib[(size_t)sa * 8]         = h4;
    *(uint4*)&ib[(size_t)(512 + sa) * 8] = l4;
    return;
  }

  int job = blockIdx.x - 4096;        // ---- W B-image job ----
  const float* W; unsigned short* img; int N;
  if (job < 32)      { W = Wv;   img = WvC;   N = 512; }
  else if (job < 64) { W = Wres; img = WresC; N = 512; job -= 32; }
  else if (job < 80) { W = Wq;   img = WqC;   N = KRANK; job -= 64; }
  else               { W = Wk;   img = WkC;   N = KRANK; job -= 80; }
  const int nt = (N == 512) ? (job >> 4) : 0;
  const int kt = job & 15;

  unsigned short* ib = img + (size_t)(nt * 16 + kt) * 16384;  // 2048 cells * 8 ush
#pragma unroll
  for (int h = 0; h < 2; ++h) {
    const int row = nt * 256 + h * 128 + srow;
    float4 v0 = make_float4(0.f, 0.f, 0.f, 0.f), v1 = v0;
    if (row < N) {
      v0 = *(const float4*)&W[(size_t)row * 512 + kt * 32 + sk4 * 8];
      v1 = *(const float4*)&W[(size_t)row * 512 + kt * 32 + sk4 * 8 + 4];
    }
    uint4 h4, l4; cvt8(v0, v1, h4, l4);
    const int cell = h * 512 + sa;
    *(uint4*)&ib[(size_t)cell * 8]          = h4;
    *(uint4*)&ib[(size_t)(1024 + cell) * 8] = l4;
  }
}

// ================= MFMA hi/lo GEMM =================
// out[m][n] = sum_k A[m][k]*W[n][k] (+bias).  M=32768, K=512.
// MODE 4/1: tile 128m x 256n, 8 waves 2m x 4n, wave 64x64 = 4x4 frags.
//   TWO-PRODUCT (ah*bh + al*bh): B-lo never staged/read. The dropped ah*bl term is
//   ~2^-9 relative -- below MODE4's bf16 output quantum and MODE1's error floor.
// MODE 5 (merged Q/K proj, bx=0->Q bx=1->K): tile 128m x 160n, 8 waves 4m x 2n,
//   wave 32x80 = 2x5 frags; THREE products (full fp32 accuracy -- feeds softmax).
// AGL=1: A staged via 2 glds16 from pre-converted Ximg. AGL=0: reg-stage + cvt8.
template<int MODE, int AGL>
__global__ __launch_bounds__(512, 4)
void mgemm_nt(const float* __restrict__ A, const unsigned short* __restrict__ Ximg,
              const unsigned short* __restrict__ Wimg,
              const float* __restrict__ bias, float* __restrict__ out,
              const float* __restrict__ xres, const float* __restrict__ gammap,
              unsigned short* __restrict__ aux,
              const unsigned short* __restrict__ Wimg2,
              const float* __restrict__ bias2,
              unsigned short* __restrict__ aux2)
{
  // regions (ushort offsets): AH 0 (4096), AL 4096, BH 8192 (8192), BL 16384. 49152 B.
  __shared__ __align__(16) unsigned short lds[24576];
  constexpr int NI  = (MODE == 5) ? 2 : 4;    // m-frags per wave
  constexpr int NJ  = (MODE == 5) ? 5 : 4;    // n-frags per wave
  constexpr int NCW = (MODE == 5) ? 80 : 64;  // wave col width
  constexpr bool TWOP = (MODE == 4 || MODE == 1);   // drop ah*bl correction
  const int tid = threadIdx.x;
  const int m0  = blockIdx.y * 128;
  const int bx  = blockIdx.x;

  const unsigned short* img = (MODE == 5) ? (bx ? Wimg2 : Wimg)
                                          : Wimg + (size_t)(bx * 16) * 16384;
  const float* bias_u = (MODE == 5 && bx) ? bias2 : bias;
  unsigned short* aux_u = (MODE == 5 && bx) ? aux2 : aux;

  // ---- A staging geometry (AGL=0 path) ----
  const int srow = tid >> 2, sk4 = tid & 3;
  const int sa16 = sa16f(srow, sk4);
  const float* ap = A + (size_t)(m0 + srow) * 512 + sk4 * 8;

  // ---- fragment geometry ----
  const int lane = tid & 63, w = tid >> 6;
  const int wm = (MODE == 5) ? (w >> 1) : (w >> 2);
  const int wn = (MODE == 5) ? (w & 1) : (w & 3);
  const int arb = wm * ((MODE == 5) ? 32 : 64);          // wave m rowbase
  const int cq = lane & 15, quad = lane >> 4;
  const int fsub = (((cq & 1) << 2) | quad) ^ (cq >> 1);
  const int foff = ((cq >> 1) << 3) + fsub;              // lane cell offset

  const unsigned short* ibase = img + (size_t)(w * 64 + lane) * 8;
  const unsigned short* xibase = Ximg + (size_t)(m0 >> 7) * 16 * 8192
                               + (size_t)(w * 64 + lane) * 8;

  f32x4 acc[NI][NJ];
#pragma unroll
  for (int i = 0; i < NI; ++i)
#pragma unroll
    for (int j = 0; j < NJ; ++j) acc[i][j] = (f32x4){0.f, 0.f, 0.f, 0.f};

  for (int kt = 0; kt < 512; kt += 32) {
    uint4 ahi, alo;
    if (AGL == 0) {
      const float4 av0 = *(const float4*)(ap + kt);
      const float4 av1 = *(const float4*)(ap + kt + 4);
      cvt8(av0, av1, ahi, alo);
    }

    __syncthreads();   // A: previous tile's readers done
    if (AGL == 0) {
      *(uint4*)&lds[       sa16 * 8] = ahi;
      *(uint4*)&lds[4096 + sa16 * 8] = alo;
    } else {
      const unsigned short* xs = xibase + (size_t)(kt >> 5) * 8192;
      glds16(xs,                   &lds[(w * 64) * 8]);
      glds16(xs + (size_t)512 * 8, &lds[4096 + (w * 64) * 8]);
    }
    const unsigned short* src = ibase + (size_t)(kt >> 5) * 16384;
    if (MODE == 5) {
      glds16(src,                         &lds[8192 + (w * 64) * 8]);
      if (w < 2) glds16(src + 4096,       &lds[8192 + (512 + w * 64) * 8]);
      glds16(src + 8192,                  &lds[8192 + (1024 + w * 64) * 8]);
      if (w < 2) glds16(src + 12288,      &lds[8192 + (1536 + w * 64) * 8]);
    } else {
#pragma unroll
      for (int c = 0; c < (TWOP ? 2 : 4); ++c)
        glds16(src + (size_t)c * 4096, &lds[8192 + (c * 512 + w * 64) * 8]);
    }
    __syncthreads();   // B: ds + vmem->lds drained, staging visible

    bf16x8 ah[NI], al_[NI];
#pragma unroll
    for (int i = 0; i < NI; ++i) {
      const int ac = (arb + i * 16) * 4 + foff;
      ah[i]  = u2b(*(const uint4*)&lds[       ac * 8]);
      al_[i] = u2b(*(const uint4*)&lds[4096 + ac * 8]);
    }
#pragma unroll
    for (int j = 0; j < NJ; ++j) {
      const int rb = wn * NCW + j * 16;
      const int bc = (rb >> 7) * 512 + (rb & 127) * 4 + foff;
      const bf16x8 bh = u2b(*(const uint4*)&lds[8192 + bc * 8]);
#pragma unroll
      for (int i = 0; i < NI; ++i) {
        acc[i][j] = __builtin_amdgcn_mfma_f32_16x16x32_bf16(ah[i],  bh, acc[i][j], 0, 0, 0);
        acc[i][j] = __builtin_amdgcn_mfma_f32_16x16x32_bf16(al_[i], bh, acc[i][j], 0, 0, 0);
      }
      if constexpr (!TWOP) {
        const bf16x8 bl = u2b(*(const uint4*)&lds[16384 + bc * 8]);
#pragma unroll
        for (int i = 0; i < NI; ++i)
          acc[i][j] = __builtin_amdgcn_mfma_f32_16x16x32_bf16(ah[i], bl, acc[i][j], 0, 0, 0);
      }
    }
  }

  // ---- epilogue: C frag elem (i,j,r): m = m0+arb+i*16+quad*4+r, n = n0b+wn*NCW+j*16+cq
  const int n0b = (MODE == 5) ? 0 : bx * 256;
  const int mb = m0 + arb + quad * 4;
  const int nb = n0b + wn * NCW + cq;

  if (MODE == 1) {
    const float g = gammap[0];
#pragma unroll
    for (int j = 0; j < NJ; ++j) {
      const float bvj = bias_u[nb + j * 16];
#pragma unroll
      for (int i = 0; i < NI; ++i) {
#pragma unroll
        for (int r = 0; r < 4; ++r) {
          const size_t off = (size_t)(mb + i * 16 + r) * 512 + (nb + j * 16);
          out[off] = fmaf(g, acc[i][j][r] + bvj, xres[off]);
        }
      }
    }
  } else if (MODE == 4) {  // VT[b][n][key] bf16
    const int b = m0 >> 12;
    const int key0 = (m0 & 4095) + arb + quad * 4;
#pragma unroll
    for (int j = 0; j < NJ; ++j) {
      const float bvj = bias_u[nb + j * 16];
      const size_t rowo = (size_t)(b * 512 + nb + j * 16) * 4096;
#pragma unroll
      for (int i = 0; i < NI; ++i) {
        unsigned short o4[4];
#pragma unroll
        for (int r = 0; r < 4; ++r) o4[r] = f2bf(acc[i][j][r] + bvj);
        uint2 o;
        o.x = (unsigned int)o4[0] | ((unsigned int)o4[1] << 16);
        o.y = (unsigned int)o4[2] | ((unsigned int)o4[3] << 16);
        *(uint2*)&aux_u[rowo + key0 + i * 16] = o;
      }
    }
  } else {  // MODE 5: Q (bx=0) / K (bx=1); n = wn*80 + j*16 + cq in [0,160)
#pragma unroll
    for (int j = 0; j < NJ; ++j) {
      const int n = nb + j * 16;
      const float bvj = (n < KRANK) ? bias_u[n] : 0.f;
#pragma unroll
      for (int i = 0; i < NI; ++i) {
#pragma unroll
        for (int r = 0; r < 4; ++r) {
          const int m = mb + i * 16 + r;
          float v = (n < KRANK) ? (acc[i][j][r] + bvj) : 0.f;
          if (bx == 0 && n < KRANK) out[(size_t)m * KRANK + n] = v;
          const unsigned short hh = f2bf(v);
          aux_u[(size_t)m * 320 + n] = hh;
          const float hf = __uint_as_float(((uint32_t)hh) << 16);
          aux_u[(size_t)m * 320 + 160 + n] = f2bf(v - hf);
        }
      }
    }
  }
}

// ================= MFMA flash attention (v12: swapped QK^T softmax) =============
// 256 blocks: b = bid&7 (XCD-affine), qt = bid>>3. Block = 128 q-rows x 512 cols.
// S phase SWAPPED: S = mfma(K, Q) -> lane holds one q-row (row=cq), keys quad*4+r
// (S0: keys 0-15, S1: keys 16-31). Softmax: scalar m/l per lane, reg-max + 2 shfl,
// reg-sum + 2 shfl, P stored as 2 aligned b64. PV: wave (p=w>>1,h=w&1) owns row-tiles
// {2p,2p+1} x col-half h. Measured R9/R10: 361-367 us, MfmaUtil ~32.
// R11 lesson: v13 async-dbuf glds16 cut conflicts 10x but was NOT faster (conflicts
// off critical path; +VALU addr math) -> keep v12. R7 lesson: do NOT grow S regs.
__global__ __launch_bounds__(512, 2)
void attn_mfma(const unsigned short* __restrict__ Qc,   // [32768][320] hi|lo
               const unsigned short* __restrict__ Kc,   // [32768][320] hi|lo
               const unsigned short* __restrict__ VT,   // [8][512][4096] bf16
               float* __restrict__ O)                   // [32768][512] fp32
{
  // klds 32x328 (10496) + vtl 4x4112 (16448) + plds 8x640 (5120) = 32064 ush
  // + alw 128 f32 (256) + updf 8 u32 (16) + linv 128 f32 (256) = 32592 ush = 65184 B
  __shared__ __align__(16) unsigned short smem[32592];
  unsigned short* klds = smem;              // 32 keys x 328 (320 data + 8 pad)
  unsigned short* vtl  = smem + 10496;      // 4 planes x [512 cols][8 keys]
  unsigned short* plds = smem + 26944;      // per-wave 16 rows x 40
  float*    alw   = (float*)(smem + 32064); // [wave][16 rows] rescale alpha
  unsigned* updf  = (unsigned*)(smem + 32320); // [wave] rescale flag
  float*    linvp = (float*)(smem + 32336); // [wave][16 rows] 1/l (epilogue)

  const int bid = blockIdx.x;
  const int b   = bid & 7;                  // XCD-affine batch
  const int qt  = bid >> 3;                 // 0..31
  const int r0  = (b << 12) + qt * 128;

  const int tid  = threadIdx.x;             // 0..511
  const int w    = tid >> 6;                // 0..7
  const int lane = tid & 63;
  const int quad = lane >> 4;
  const int cq   = lane & 15;
  const int p    = w >> 1;                  // PV row-pair
  const int h    = w & 1;                   // PV col-half

  // ---- persistent Q fragments (B-operand layout), rows r0+w*16+cq ----
  bf16x8 qhi[5], qlo[5];
  {
    const size_t qrow = (size_t)(r0 + w * 16 + cq) * 320;
#pragma unroll
    for (int c = 0; c < 5; ++c) {
      qhi[c] = u2b(*(const uint4*)(Qc + qrow + c * 32 + quad * 8));
      qlo[c] = u2b(*(const uint4*)(Qc + qrow + 160 + c * 32 + quad * 8));
    }
  }

  f32x4 acc4[32];   // [ct] = rows tile 2p, [16+ct] = rows tile 2p+1; cols h*256+ct*16
#pragma unroll
  for (int i = 0; i < 32; ++i) acc4[i] = (f32x4){0.f, 0.f, 0.f, 0.f};
  float mreg = -3.0e38f, lreg = 0.f;        // scalar: lane owns row cq

  const int vqd = (tid & 3) * 8;        // V key sub-offset (8 ushorts) = plane index *8
  const int vc  = tid >> 2;             // 0..127 column group
  const int vwb = (tid & 3) * 4112 + vc * 8;     // LDS write base (plane, col)
  const int vrb = quad * 4112 + h * 2048 + cq * 8;  // LDS read base (+ ct*128)

  // K staging geometry (1280 uint4 cells): p = tid, tid+512, (tid<256: tid+1024)
  const int krow0 = tid / 40,          kc0 = (tid - krow0 * 40) * 8;
  const int krow1 = (tid + 512) / 40,  kc1 = ((tid + 512) - krow1 * 40) * 8;
  const int krow2 = (tid + 1024) / 40, kc2 = ((tid + 1024) - krow2 * 40) * 8;

  uint4 pk0, pk1, pk2, pv0, pv1, pv2, pv3;
  // ---- initial prefetch (tile 0) ----
  const unsigned short* kbase = Kc + (size_t)(b * 4096) * 320;
  const unsigned short* vbase = VT + ((size_t)(b * 512 + vc)) * 4096 + vqd;
  {
    pk0 = *(const uint4*)(kbase + (size_t)tid * 8);
    pk1 = *(const uint4*)(kbase + (size_t)(tid + 512) * 8);
    if (tid < 256) pk2 = *(const uint4*)(kbase + (size_t)(tid + 1024) * 8);
    pv0 = *(const uint4*)(vbase);
    pv1 = *(const uint4*)(vbase + (size_t)128 * 4096);
    pv2 = *(const uint4*)(vbase + (size_t)256 * 4096);
    pv3 = *(const uint4*)(vbase + (size_t)384 * 4096);
  }

  for (int kt = 0; kt < 128; ++kt) {
    __syncthreads();  // A: previous tile's LDS readers done; drains prefetch loads

    // ---- stage prefetched K / V tiles into LDS ----
    *(uint4*)&klds[krow0 * 328 + kc0] = pk0;
    *(uint4*)&klds[krow1 * 328 + kc1] = pk1;
    if (tid < 256) *(uint4*)&klds[krow2 * 328 + kc2] = pk2;
    *(uint4*)&vtl[vwb]        = pv0;
    *(uint4*)&vtl[vwb + 1024] = pv1;
    *(uint4*)&vtl[vwb + 2048] = pv2;
    *(uint4*)&vtl[vwb + 3072] = pv3;

    __syncthreads();  // B: staging visible

    // ---- issue prefetch for next tile (in flight during S+softmax+PV) ----
    {
      const int ktn = (kt < 127) ? kt + 1 : 127;
      pk0 = *(const uint4*)(kbase + (size_t)(ktn * 32 * 320) + (size_t)tid * 8);
      pk1 = *(const uint4*)(kbase + (size_t)(ktn * 32 * 320) + (size_t)(tid + 512) * 8);
      if (tid < 256) pk2 = *(const uint4*)(kbase + (size_t)(ktn * 32 * 320) + (size_t)(tid + 1024) * 8);
      pv0 = *(const uint4*)(vbase + ktn * 32);
      pv1 = *(const uint4*)(vbase + (size_t)128 * 4096 + ktn * 32);
      pv2 = *(const uint4*)(vbase + (size_t)256 * 4096 + ktn * 32);
      pv3 = *(const uint4*)(vbase + (size_t)384 * 4096 + ktn * 32);
    }

    // ---- S phase (swapped): S0 = K[0:16].Q^T, S1 = K[16:32].Q^T ----
    f32x4 S0 = (f32x4){0.f, 0.f, 0.f, 0.f};
    f32x4 S1 = (f32x4){0.f, 0.f, 0.f, 0.f};
    __builtin_amdgcn_s_setprio(1);
#pragma unroll
    for (int c = 0; c < 5; ++c) {
      const int ko = c * 32 + quad * 8;
      const bf16x8 kh0 = u2b(*(const uint4*)&klds[cq * 328 + ko]);
      const bf16x8 kl0 = u2b(*(const uint4*)&klds[cq * 328 + 160 + ko]);
      const bf16x8 kh1 = u2b(*(const uint4*)&klds[(16 + cq) * 328 + ko]);
      const bf16x8 kl1 = u2b(*(const uint4*)&klds[(16 + cq) * 328 + 160 + ko]);
      S0 = __builtin_amdgcn_mfma_f32_16x16x32_bf16(kh0, qhi[c], S0, 0, 0, 0);
      S1 = __builtin_amdgcn_mfma_f32_16x16x32_bf16(kh1, qhi[c], S1, 0, 0, 0);
      S0 = __builtin_amdgcn_mfma_f32_16x16x32_bf16(kl0, qhi[c], S0, 0, 0, 0);
      S1 = __builtin_amdgcn_mfma_f32_16x16x32_bf16(kl1, qhi[c], S1, 0, 0, 0);
      S0 = __builtin_amdgcn_mfma_f32_16x16x32_bf16(kh0, qlo[c], S0, 0, 0, 0);
      S1 = __builtin_amdgcn_mfma_f32_16x16x32_bf16(kh1, qlo[c], S1, 0, 0, 0);
    }
    __builtin_amdgcn_s_setprio(0);

    // ---- scalar online softmax for row cq (defer-max THR=8) ----
    unsigned short* pw = plds + w * 640;
    float t = fmaxf(fmaxf(S0[0], S0[1]), fmaxf(S0[2], S0[3]));
    t = fmaxf(t, fmaxf(fmaxf(S1[0], S1[1]), fmaxf(S1[2], S1[3])));
    t = fmaxf(t, __shfl_xor(t, 16));
    t = fmaxf(t, __shfl_xor(t, 32));
    const bool need = (t > mreg + 8.f);
    const float mn = need ? t : mreg;
    const float al = need ? __expf(mreg - mn) : 1.f;
    mreg = mn;
    float pv[8];
#pragma unroll
    for (int r = 0; r < 4; ++r) { pv[r] = __expf(S0[r] - mn); pv[4 + r] = __expf(S1[r] - mn); }
    float ts = ((pv[0] + pv[1]) + (pv[2] + pv[3])) + ((pv[4] + pv[5]) + (pv[6] + pv[7]));
    ts += __shfl_xor(ts, 16);
    ts += __shfl_xor(ts, 32);
    lreg = lreg * al + ts;
    {
      unsigned short q0 = f2bf(pv[0]), q1 = f2bf(pv[1]), q2 = f2bf(pv[2]), q3 = f2bf(pv[3]);
      unsigned short q4 = f2bf(pv[4]), q5 = f2bf(pv[5]), q6 = f2bf(pv[6]), q7 = f2bf(pv[7]);
      uint2 o0, o1;
      o0.x = (unsigned)q0 | ((unsigned)q1 << 16); o0.y = (unsigned)q2 | ((unsigned)q3 << 16);
      o1.x = (unsigned)q4 | ((unsigned)q5 << 16); o1.y = (unsigned)q6 | ((unsigned)q7 << 16);
      *(uint2*)&pw[cq * 40 + quad * 4]      = o0;   // keys quad*4..+3
      *(uint2*)&pw[cq * 40 + 16 + quad * 4] = o1;   // keys 16+quad*4..+3
    }
    if (lane < 16) alw[w * 16 + lane] = al;
    const bool anyu = __any(need);
    if (lane == 0) updf[w] = anyu ? 1u : 0u;

    __syncthreads();  // C: P, alpha, upd flags visible to all waves

    // ---- PV phase: rows tiles {2p,2p+1} x cols [h*256, h*256+256) ----
    const unsigned short* pb = plds + (2 * p) * 640 + cq * 40 + quad * 8;
    const bf16x8 pa0 = u2b(*(const uint4*)pb);
    const bf16x8 pa1 = u2b(*(const uint4*)(pb + 640));

    if (updf[2 * p] | updf[2 * p + 1]) {   // rare under defer-max
      float aA[4], aB[4];
#pragma unroll
      for (int r = 0; r < 4; ++r) {
        aA[r] = alw[(2 * p) * 16 + quad * 4 + r];
        aB[r] = alw[(2 * p + 1) * 16 + quad * 4 + r];
      }
#pragma unroll
      for (int ct = 0; ct < 16; ++ct) {
#pragma unroll
        for (int r = 0; r < 4; ++r) {
          acc4[ct][r]      *= aA[r];
          acc4[16 + ct][r] *= aB[r];
        }
      }
    }

    __builtin_amdgcn_s_setprio(1);
#pragma unroll
    for (int ct = 0; ct < 16; ++ct) {
      const bf16x8 vb = u2b(*(const uint4*)&vtl[vrb + ct * 128]);
      acc4[ct]      = __builtin_amdgcn_mfma_f32_16x16x32_bf16(pa0, vb, acc4[ct], 0, 0, 0);
      acc4[16 + ct] = __builtin_amdgcn_mfma_f32_16x16x32_bf16(pa1, vb, acc4[16 + ct], 0, 0, 0);
    }
    __builtin_amdgcn_s_setprio(0);
  }

  // ---- epilogue: O = acc/l, cross-wave 1/l via LDS, staged through LDS ----
  if (lane < 16) linvp[w * 16 + lane] = 1.f / lreg;
  __syncthreads();  // linv visible + all waves done with klds/vtl before overlay

  float invv[2][4];
#pragma unroll
  for (int rt = 0; rt < 2; ++rt)
#pragma unroll
    for (int r = 0; r < 4; ++r)
      invv[rt][r] = linvp[(2 * p + rt) * 16 + quad * 4 + r];

  float* ep = (float*)smem + w * 1088;     // 16 rows x 68 fp32 per wave (4352 B)
#pragma unroll
  for (int rt = 0; rt < 2; ++rt) {
    const int rowb = r0 + (2 * p + rt) * 16;
#pragma unroll
    for (int g = 0; g < 4; ++g) {
#pragma unroll
      for (int ii = 0; ii < 4; ++ii)
#pragma unroll
        for (int r = 0; r < 4; ++r)
          ep[(quad * 4 + r) * 68 + ii * 16 + cq] = acc4[rt * 16 + g * 4 + ii][r] * invv[rt][r];
      // wave-private RAW; ds ops complete in order per wave
#pragma unroll
      for (int t2 = 0; t2 < 4; ++t2) {
        const int flat4 = t2 * 64 + lane;  // 0..255 float4 units (16 rows x 16)
        const int row = flat4 >> 4;        // 0..15
        const int c4 = flat4 & 15;
        const float4 val = *(const float4*)&ep[row * 68 + c4 * 4];
        *(float4*)&O[(size_t)(rowb + row) * CDIM + h * 256 + g * 64 + c4 * 4] = val;
      }
    }
  }
}

extern "C" void kernel_launch(void* const* d_in, const int* in_sizes, int n_in,
                              void* d_out, int out_size, void* d_ws, size_t ws_size,
                              hipStream_t stream)
{
  const float* x     = (const float*)d_in[0];
  const float* Wq    = (const float*)d_in[1];
  const float* bq    = (const float*)d_in[2];
  const float* Wk    = (const float*)d_in[3];
  const float* bk    = (const float*)d_in[4];
  const float* Wv    = (const float*)d_in[5];
  const float* bv    = (const float*)d_in[6];
  const float* Wres  = (const float*)d_in[7];
  const float* bres  = (const float*)d_in[8];
  const float* gamma = (const float*)d_in[9];

  float* seg_map  = (float*)d_out;                         // 32768 x 150
  float* feat_map = seg_map + (size_t)M_ROWS * KRANK;      // 32768 x 512

  unsigned short* Qcomb = (unsigned short*)d_ws;                       // [32768][320]
  unsigned short* Kcomb = Qcomb + (size_t)M_ROWS * 320;                // [32768][320]
  unsigned short* VTb   = Kcomb + (size_t)M_ROWS * 320;                // [8][512][4096]
  float*          feats = (float*)(VTb + (size_t)M_ROWS * CDIM);       // [32768][512]
  unsigned short* WvC   = (unsigned short*)(feats + (size_t)M_ROWS * CDIM); // 2x16 images
  unsigned short* WresC = WvC   + (size_t)2 * 16 * 16384;
  unsigned short* WqC   = WresC + (size_t)2 * 16 * 16384;              // 1x16 images
  unsigned short* WkC   = WqC   + (size_t)16 * 16384;
  // x A-images (64 MB) overlay the feats region: consumed by mgemm<5>/<4>, then
  // attn overwrites the region with feats (stream-ordered, safe).
  unsigned short* XiC   = (unsigned short*)feats;                      // 4096 x 8192 ush

  cvt_all<<<dim3(4192), dim3(512), 0, stream>>>(x, XiC, Wv, Wres, Wq, Wk, WvC, WresC, WqC, WkC);
  mgemm_nt<5, 1><<<dim3(2, 256), dim3(512), 0, stream>>>(x, XiC, WqC, bq, seg_map, nullptr, nullptr, Qcomb, WkC, bk, Kcomb);
  mgemm_nt<4, 1><<<dim3(2, 256), dim3(512), 0, stream>>>(x, XiC, WvC, bv, nullptr, nullptr, nullptr, VTb, nullptr, nullptr, nullptr);
  attn_mfma<<<dim3(256), dim3(512), 0, stream>>>(Qcomb, Kcomb, VTb, feats);
  mgemm_nt<1, 0><<<dim3(2, 256), dim3(512), 0, stream>>>(feats, nullptr, WresC, bres, feat_map, x, gamma, nullptr, nullptr, nullptr, nullptr);
}